// Round 2
// baseline (130.969 us; speedup 1.0000x reference)
//
#include <hip/hip_runtime.h>

#define HH 512
#define WW 512
#define CC 3
#define BANDS 16
#define BAND_ROWS 32   // HH / BANDS
#define RPW 8          // rows per wave; 4 waves per block cover a band

// d_ws layout: float partial[B*CC*BANDS][4]  (32*3*16*4 = 6144 floats = 24.6 KB)

__global__ __launch_bounds__(256, 5) void lap_block_sum_kernel(
    const float* __restrict__ gt, const float* __restrict__ sp,
    float* __restrict__ partial)
{
    __shared__ float red[4][4];

    const int band = blockIdx.x, c = blockIdx.y, b = blockIdx.z;
    const int t = threadIdx.x;
    const int wv = t >> 6, lane = t & 63;

    const size_t plane = (size_t)(b * CC + c) * (size_t)(HH * WW);
    const float* __restrict__ gtp = gt + plane;
    const float* __restrict__ spp = sp + plane;

    const int h0   = band * BAND_ROWS + wv * RPW;
    const int colA = 4 * lane;          // cols [colA, colA+4)
    const int colB = 256 + 4 * lane;    // cols [colB, colB+4)

    // hz block index per row-phase m = (c*512+h) % 3; constant over a lane's 4 cols
    const int hzA_0 = (colA) / 384, hzA_1 = (512 + colA) / 384, hzA_2 = (1024 + colA) / 384;
    const int hzB_0 = (colB) / 384, hzB_1 = (512 + colB) / 384, hzB_2 = (1024 + colB) / 384;

    // 3-row register ring of t = gt - sp, plus left/right neighbor scalars
    float dA[3][4], dB[3][4];
    float lnA[3], rnA[3], lnB[3], rnB[3];

#define LOAD_ROW(HR, S) do {                                                  \
        int hs_ = (HR); hs_ = hs_ < 0 ? 1 : (hs_ > HH - 1 ? HH - 2 : hs_);    \
        const float* gr_ = gtp + (size_t)hs_ * WW;                            \
        const float* sr_ = spp + (size_t)hs_ * WW;                            \
        float4 ga_ = *(const float4*)(gr_ + colA);                            \
        float4 gb_ = *(const float4*)(gr_ + colB);                            \
        float4 sa_ = *(const float4*)(sr_ + colA);                            \
        float4 sb_ = *(const float4*)(sr_ + colB);                            \
        dA[S][0] = ga_.x - sa_.x; dA[S][1] = ga_.y - sa_.y;                   \
        dA[S][2] = ga_.z - sa_.z; dA[S][3] = ga_.w - sa_.w;                   \
        dB[S][0] = gb_.x - sb_.x; dB[S][1] = gb_.y - sb_.y;                   \
        dB[S][2] = gb_.z - sb_.z; dB[S][3] = gb_.w - sb_.w;                   \
        float lA_  = __shfl(dA[S][3], lane - 1);                              \
        float rA_  = __shfl(dA[S][0], lane + 1);                              \
        float lB_  = __shfl(dB[S][3], lane - 1);                              \
        float rB_  = __shfl(dB[S][0], lane + 1);                              \
        float xAB_ = __shfl(dB[S][0], 0);   /* col 256, for lane63's rnA */   \
        float xBA_ = __shfl(dA[S][3], 63);  /* col 255, for lane0's lnB */    \
        lnA[S] = (lane == 0)  ? dA[S][1] : lA_;  /* reflect col -1 -> 1 */    \
        rnA[S] = (lane == 63) ? xAB_     : rA_;                               \
        lnB[S] = (lane == 0)  ? xBA_     : lB_;                               \
        rnB[S] = (lane == 63) ? dB[S][2] : rB_;  /* reflect col 512 -> 510 */ \
    } while (0)

    LOAD_ROW(h0 - 1, 0);
    LOAD_ROW(h0,     1);

    float acc0 = 0.f, acc1 = 0.f, acc2 = 0.f, acc3 = 0.f;
    int m = (c * HH + h0) % 3;

    #pragma unroll
    for (int i = 0; i < RPW; ++i) {
        const int sB_ = (i + 2) % 3, sT = i % 3, sM = (i + 1) % 3; // static after unroll
        LOAD_ROW(h0 + i + 1, sB_);

        float csA0 = dA[sT][0] + dA[sM][0] + dA[sB_][0];
        float csA1 = dA[sT][1] + dA[sM][1] + dA[sB_][1];
        float csA2 = dA[sT][2] + dA[sM][2] + dA[sB_][2];
        float csA3 = dA[sT][3] + dA[sM][3] + dA[sB_][3];
        float csLA = lnA[sT] + lnA[sM] + lnA[sB_];
        float csRA = rnA[sT] + rnA[sM] + rnA[sB_];
        float sA = fabsf(csLA + csA0 + csA1 - 9.f * dA[sM][0])
                 + fabsf(csA0 + csA1 + csA2 - 9.f * dA[sM][1])
                 + fabsf(csA1 + csA2 + csA3 - 9.f * dA[sM][2])
                 + fabsf(csA2 + csA3 + csRA - 9.f * dA[sM][3]);

        float csB0 = dB[sT][0] + dB[sM][0] + dB[sB_][0];
        float csB1 = dB[sT][1] + dB[sM][1] + dB[sB_][1];
        float csB2 = dB[sT][2] + dB[sM][2] + dB[sB_][2];
        float csB3 = dB[sT][3] + dB[sM][3] + dB[sB_][3];
        float csLB = lnB[sT] + lnB[sM] + lnB[sB_];
        float csRB = rnB[sT] + rnB[sM] + rnB[sB_];
        float sB = fabsf(csLB + csB0 + csB1 - 9.f * dB[sM][0])
                 + fabsf(csB0 + csB1 + csB2 - 9.f * dB[sM][1])
                 + fabsf(csB1 + csB2 + csB3 - 9.f * dB[sM][2])
                 + fabsf(csB2 + csB3 + csRB - 9.f * dB[sM][3]);

        int hzA = (m == 0) ? hzA_0 : ((m == 1) ? hzA_1 : hzA_2);
        int hzB = (m == 0) ? hzB_0 : ((m == 1) ? hzB_1 : hzB_2);
        acc0 += ((hzA == 0) ? sA : 0.f) + ((hzB == 0) ? sB : 0.f);
        acc1 += ((hzA == 1) ? sA : 0.f) + ((hzB == 1) ? sB : 0.f);
        acc2 += ((hzA == 2) ? sA : 0.f) + ((hzB == 2) ? sB : 0.f);
        acc3 += ((hzA == 3) ? sA : 0.f) + ((hzB == 3) ? sB : 0.f);

        m = (m == 2) ? 0 : (m + 1);
    }
#undef LOAD_ROW

    // wave64 butterfly reduce
    #pragma unroll
    for (int off = 32; off > 0; off >>= 1) {
        acc0 += __shfl_xor(acc0, off);
        acc1 += __shfl_xor(acc1, off);
        acc2 += __shfl_xor(acc2, off);
        acc3 += __shfl_xor(acc3, off);
    }
    if (lane == 0) {
        red[wv][0] = acc0 * 0.0625f; red[wv][1] = acc1 * 0.0625f;
        red[wv][2] = acc2 * 0.0625f; red[wv][3] = acc3 * 0.0625f;
    }
    __syncthreads();
    if (t < 4) {
        const int wg = band + BANDS * (c + CC * b);
        partial[wg * 4 + t] = red[0][t] + red[1][t] + red[2][t] + red[3][t];
    }
}

__global__ void finalize_kernel(const float* __restrict__ partial,
                                float* __restrict__ out, int B)
{
    __shared__ float bmax[32];
    const int t = threadIdx.x;                  // 512 threads
    const int b = t >> 4, v = (t >> 2) & 3, hz = t & 3;
    float s = 0.f;
    if (b < B) {
        #pragma unroll
        for (int c = 0; c < CC; ++c) {
            #pragma unroll
            for (int band = 0; band < BANDS; ++band) {
                if ((c * HH + band * BAND_ROWS) / 384 == v)
                    s += partial[(band + BANDS * (c + CC * b)) * 4 + hz];
            }
        }
    }
    // max over the 16 (v,hz) threads of each b (aligned 16-groups in a wave)
    #pragma unroll
    for (int off = 8; off > 0; off >>= 1)
        s = fmaxf(s, __shfl_xor(s, off));
    if ((t & 15) == 0) bmax[b] = (b < B) ? s : 0.f;
    __syncthreads();
    if (t < 64) {
        float x = (t < 32) ? bmax[t] : 0.f;
        #pragma unroll
        for (int off = 16; off > 0; off >>= 1)
            x += __shfl_down(x, off);
        if (t == 0) out[0] = x;
    }
}

extern "C" void kernel_launch(void* const* d_in, const int* in_sizes, int n_in,
                              void* d_out, int out_size, void* d_ws, size_t ws_size,
                              hipStream_t stream) {
    const float* gt = (const float*)d_in[0];
    const float* sp = (const float*)d_in[1];
    float* partial = (float*)d_ws;
    float* out = (float*)d_out;

    const int B = in_sizes[0] / (CC * HH * WW);  // 32

    dim3 grid(BANDS, CC, B);
    lap_block_sum_kernel<<<grid, 256, 0, stream>>>(gt, sp, partial);

    finalize_kernel<<<1, 512, 0, stream>>>(partial, out, B);
}

// Round 3
// 43.395 us; speedup vs baseline: 3.0181x; 3.0181x over previous
//
#include <hip/hip_runtime.h>

#define HH 512
#define WW 512
#define CC 3
#define BANDS 16
#define BAND_ROWS 32
#define RPW 8   // rows per wave, 4 waves per 256-thread WG cover a band

// d_ws layout: float partial[B*CC*BANDS][4]

__global__ __launch_bounds__(256, 2) void lap_block_sum_kernel(
    const float* __restrict__ gt, const float* __restrict__ sp,
    float* __restrict__ partial)
{
    __shared__ float ldsr[8][WW];   // [2*wv]=wave's d[0] row, [2*wv+1]=wave's d[7] row
    __shared__ float red[4][4];

    const int band = blockIdx.x, c = blockIdx.y, b = blockIdx.z;
    const int t = threadIdx.x;
    const int wv = t >> 6, lane = t & 63;

    const size_t plane = (size_t)(b * CC + c) * (size_t)(HH * WW);
    const float* __restrict__ gtp = gt + plane;
    const float* __restrict__ spp = sp + plane;

    const int h0   = band * BAND_ROWS + wv * RPW;
    const int colA = 4 * lane;
    const int colB = 256 + 4 * lane;

    // ---- phase 1: issue ALL loads (halo first), then diff ----
    float hA[4], hB[4];   // wave0: top halo row h0-1; wave3: bottom halo row h0+8
    {
        int hs = (wv == 0) ? h0 - 1 : h0 + RPW;
        hs = hs < 0 ? 1 : (hs > HH - 1 ? HH - 2 : hs);
        if (wv == 0 || wv == 3) {
            const float* gr = gtp + (size_t)hs * WW;
            const float* sr = spp + (size_t)hs * WW;
            float4 ga = *(const float4*)(gr + colA);
            float4 gb = *(const float4*)(gr + colB);
            float4 sa = *(const float4*)(sr + colA);
            float4 sb = *(const float4*)(sr + colB);
            hA[0]=ga.x-sa.x; hA[1]=ga.y-sa.y; hA[2]=ga.z-sa.z; hA[3]=ga.w-sa.w;
            hB[0]=gb.x-sb.x; hB[1]=gb.y-sb.y; hB[2]=gb.z-sb.z; hB[3]=gb.w-sb.w;
        }
    }

    float dA[RPW][4], dB[RPW][4];
    #pragma unroll
    for (int r = 0; r < RPW; ++r) {
        const float* gr = gtp + (size_t)(h0 + r) * WW;
        const float* sr = spp + (size_t)(h0 + r) * WW;
        float4 ga = *(const float4*)(gr + colA);
        float4 gb = *(const float4*)(gr + colB);
        float4 sa = *(const float4*)(sr + colA);
        float4 sb = *(const float4*)(sr + colB);
        dA[r][0]=ga.x-sa.x; dA[r][1]=ga.y-sa.y; dA[r][2]=ga.z-sa.z; dA[r][3]=ga.w-sa.w;
        dB[r][0]=gb.x-sb.x; dB[r][1]=gb.y-sb.y; dB[r][2]=gb.z-sb.z; dB[r][3]=gb.w-sb.w;
    }

    // publish boundary diff rows
    *(float4*)&ldsr[2*wv  ][colA] = make_float4(dA[0][0],dA[0][1],dA[0][2],dA[0][3]);
    *(float4*)&ldsr[2*wv  ][colB] = make_float4(dB[0][0],dB[0][1],dB[0][2],dB[0][3]);
    *(float4*)&ldsr[2*wv+1][colA] = make_float4(dA[RPW-1][0],dA[RPW-1][1],dA[RPW-1][2],dA[RPW-1][3]);
    *(float4*)&ldsr[2*wv+1][colB] = make_float4(dB[RPW-1][0],dB[RPW-1][1],dB[RPW-1][2],dB[RPW-1][3]);
    __syncthreads();

    // neighbor boundary rows into regs
    float pA[4], pB[4], nA[4], nB[4];
    if (wv == 0) {
        pA[0]=hA[0]; pA[1]=hA[1]; pA[2]=hA[2]; pA[3]=hA[3];
        pB[0]=hB[0]; pB[1]=hB[1]; pB[2]=hB[2]; pB[3]=hB[3];
    } else {
        float4 a = *(const float4*)&ldsr[2*wv-1][colA];
        float4 q = *(const float4*)&ldsr[2*wv-1][colB];
        pA[0]=a.x; pA[1]=a.y; pA[2]=a.z; pA[3]=a.w;
        pB[0]=q.x; pB[1]=q.y; pB[2]=q.z; pB[3]=q.w;
    }
    if (wv == 3) {
        nA[0]=hA[0]; nA[1]=hA[1]; nA[2]=hA[2]; nA[3]=hA[3];
        nB[0]=hB[0]; nB[1]=hB[1]; nB[2]=hB[2]; nB[3]=hB[3];
    } else {
        float4 a = *(const float4*)&ldsr[2*wv+2][colA];
        float4 q = *(const float4*)&ldsr[2*wv+2][colB];
        nA[0]=a.x; nA[1]=a.y; nA[2]=a.z; nA[3]=a.w;
        nB[0]=q.x; nB[1]=q.y; nB[2]=q.z; nB[3]=q.w;
    }

    // ---- phase 2: stencil, all in registers + shfl ----
    const int hzA0 = colA/384, hzA1 = (512+colA)/384, hzA2 = (1024+colA)/384;
    const int hzB0 = colB/384, hzB1 = (512+colB)/384, hzB2 = (1024+colB)/384;
    const int lm1 = (lane + 63) & 63, lp1 = (lane + 1) & 63;

    float acc0=0.f, acc1=0.f, acc2=0.f, acc3=0.f;
    int m = (c * HH + h0) % 3;   // wave-uniform row phase

#define ROWSTEP(TA,TB,RM,BA,BB) do {                                    \
    float csA0 = TA[0]+dA[RM][0]+BA[0];                                 \
    float csA1 = TA[1]+dA[RM][1]+BA[1];                                 \
    float csA2 = TA[2]+dA[RM][2]+BA[2];                                 \
    float csA3 = TA[3]+dA[RM][3]+BA[3];                                 \
    float csB0 = TB[0]+dB[RM][0]+BB[0];                                 \
    float csB1 = TB[1]+dB[RM][1]+BB[1];                                 \
    float csB2 = TB[2]+dB[RM][2]+BB[2];                                 \
    float csB3 = TB[3]+dB[RM][3]+BB[3];                                 \
    float sA3m = __shfl(csA3, lm1), sA0p = __shfl(csA0, lp1);           \
    float sB3m = __shfl(csB3, lm1), sB0p = __shfl(csB0, lp1);           \
    float xR = __shfl(csB0, 0),     xL = __shfl(csA3, 63);              \
    float lA = (lane==0)  ? csA1 : sA3m;  /* col -1 -> reflect col 1 */ \
    float rA = (lane==63) ? xR   : sA0p;  /* col 256 */                 \
    float lB = (lane==0)  ? xL   : sB3m;  /* col 255 */                 \
    float rB = (lane==63) ? csB2 : sB0p;  /* col 512 -> reflect 510 */  \
    float sA = fabsf(lA  +csA0+csA1 - 9.f*dA[RM][0])                    \
             + fabsf(csA0+csA1+csA2 - 9.f*dA[RM][1])                    \
             + fabsf(csA1+csA2+csA3 - 9.f*dA[RM][2])                    \
             + fabsf(csA2+csA3+rA   - 9.f*dA[RM][3]);                   \
    float sB = fabsf(lB  +csB0+csB1 - 9.f*dB[RM][0])                    \
             + fabsf(csB0+csB1+csB2 - 9.f*dB[RM][1])                    \
             + fabsf(csB1+csB2+csB3 - 9.f*dB[RM][2])                    \
             + fabsf(csB2+csB3+rB   - 9.f*dB[RM][3]);                   \
    int hzA = (m==0)?hzA0:((m==1)?hzA1:hzA2);                           \
    int hzB = (m==0)?hzB0:((m==1)?hzB1:hzB2);                           \
    acc0 += ((hzA==0)?sA:0.f) + ((hzB==0)?sB:0.f);                      \
    acc1 += ((hzA==1)?sA:0.f) + ((hzB==1)?sB:0.f);                      \
    acc2 += ((hzA==2)?sA:0.f) + ((hzB==2)?sB:0.f);                      \
    acc3 += ((hzA==3)?sA:0.f) + ((hzB==3)?sB:0.f);                      \
    m = (m==2)?0:(m+1);                                                 \
} while(0)

    ROWSTEP(pA,    pB,    0, dA[1], dB[1]);
    ROWSTEP(dA[0], dB[0], 1, dA[2], dB[2]);
    ROWSTEP(dA[1], dB[1], 2, dA[3], dB[3]);
    ROWSTEP(dA[2], dB[2], 3, dA[4], dB[4]);
    ROWSTEP(dA[3], dB[3], 4, dA[5], dB[5]);
    ROWSTEP(dA[4], dB[4], 5, dA[6], dB[6]);
    ROWSTEP(dA[5], dB[5], 6, dA[7], dB[7]);
    ROWSTEP(dA[6], dB[6], 7, nA,    nB);
#undef ROWSTEP

    // wave64 butterfly reduce
    #pragma unroll
    for (int off = 32; off > 0; off >>= 1) {
        acc0 += __shfl_xor(acc0, off);
        acc1 += __shfl_xor(acc1, off);
        acc2 += __shfl_xor(acc2, off);
        acc3 += __shfl_xor(acc3, off);
    }
    if (lane == 0) {
        red[wv][0] = acc0 * 0.0625f; red[wv][1] = acc1 * 0.0625f;
        red[wv][2] = acc2 * 0.0625f; red[wv][3] = acc3 * 0.0625f;
    }
    __syncthreads();
    if (t < 4) {
        const int wg = band + BANDS * (c + CC * b);
        partial[wg * 4 + t] = red[0][t] + red[1][t] + red[2][t] + red[3][t];
    }
}

__global__ void finalize_kernel(const float* __restrict__ partial,
                                float* __restrict__ out, int B)
{
    __shared__ float bmax[32];
    const int t = threadIdx.x;                  // 512 threads
    const int b = t >> 4, v = (t >> 2) & 3, hz = t & 3;
    float s = 0.f;
    if (b < B) {
        #pragma unroll
        for (int c = 0; c < CC; ++c) {
            #pragma unroll
            for (int band = 0; band < BANDS; ++band) {
                if ((c * HH + band * BAND_ROWS) / 384 == v)
                    s += partial[(band + BANDS * (c + CC * b)) * 4 + hz];
            }
        }
    }
    #pragma unroll
    for (int off = 8; off > 0; off >>= 1)
        s = fmaxf(s, __shfl_xor(s, off));
    if ((t & 15) == 0) bmax[b] = (b < B) ? s : 0.f;
    __syncthreads();
    if (t < 64) {
        float x = (t < 32) ? bmax[t] : 0.f;
        #pragma unroll
        for (int off = 16; off > 0; off >>= 1)
            x += __shfl_down(x, off);
        if (t == 0) out[0] = x;
    }
}

extern "C" void kernel_launch(void* const* d_in, const int* in_sizes, int n_in,
                              void* d_out, int out_size, void* d_ws, size_t ws_size,
                              hipStream_t stream) {
    const float* gt = (const float*)d_in[0];
    const float* sp = (const float*)d_in[1];
    float* partial = (float*)d_ws;
    float* out = (float*)d_out;

    const int B = in_sizes[0] / (CC * HH * WW);  // 32

    dim3 grid(BANDS, CC, B);
    lap_block_sum_kernel<<<grid, 256, 0, stream>>>(gt, sp, partial);

    finalize_kernel<<<1, 512, 0, stream>>>(partial, out, B);
}